// Round 1
// baseline (379.330 us; speedup 1.0000x reference)
//
#include <hip/hip_runtime.h>
#include <hip/hip_bf16.h>

// Problem constants (B,T,S,D = 32,1024,1024,512)
#define B_ 32
#define T_ 1024
#define S_ 1024
#define D_ 512
#define M_ (B_*T_)       // 32768 GEMM rows
#define N_ D_            // 512  GEMM cols
#define K_ (2*D_)        // 1024 GEMM reduction

typedef __attribute__((ext_vector_type(8))) short bf16x8;  // 8 bf16 = 4 VGPRs
typedef __attribute__((ext_vector_type(4))) float f32x4;

__device__ inline unsigned short f2bf(float x) {
    union { float f; unsigned u; } v; v.f = x;
    unsigned r = v.u + 0x7FFFu + ((v.u >> 16) & 1u);   // RNE
    return (unsigned short)(r >> 16);
}

// ---------------------------------------------------------------------------
// Kernel 1: alignment scan (+ scatter of the attn ones).
// One wave per batch. cond is always true for T<=S (i - inserted <= 1023 < S),
// so inserted == inclusive prefix sum of flags over positions 1..t.
// ---------------------------------------------------------------------------
__global__ void align_kernel(const int* __restrict__ iv, int* __restrict__ jbuf,
                             float* __restrict__ attn) {
    const int b = blockIdx.x;          // 32 blocks x 64 threads
    const int lane = threadIdx.x;      // 0..63, 16 tokens each
    const int* row = iv + b * T_;
    int f[16];
    int local = 0;
    const int t0 = lane * 16;
    #pragma unroll
    for (int q = 0; q < 16; ++q) {
        const int t = t0 + q;
        const int tok = row[t];
        const int fl = (t > 0 && (tok == 1 || tok == 2)) ? 1 : 0;
        f[q] = fl;
        local += fl;
    }
    // wave-64 inclusive scan of per-lane sums
    int incl = local;
    #pragma unroll
    for (int off = 1; off < 64; off <<= 1) {
        const int up = __shfl_up(incl, off, 64);
        if (lane >= off) incl += up;
    }
    int run = incl - local;            // exclusive prefix at this lane's first token
    #pragma unroll
    for (int q = 0; q < 16; ++q) {
        const int t = t0 + q;
        run += f[q];
        int j;
        if (t == 0) {
            j = 0;                     // attn[b,0,0] = 1 always
        } else {
            j = t - run - 1;
            if (j < 0) j += S_;        // torch negative-index wrap
        }
        jbuf[b * T_ + t] = j;
        attn[(size_t)(b * T_ + t) * S_ + j] = 1.0f;   // valid always true here
    }
}

// ---------------------------------------------------------------------------
// Kernel 2: W [512,1024] f32 -> bf16
// ---------------------------------------------------------------------------
__global__ void pack_w(const float* __restrict__ W, unsigned short* __restrict__ Wbf) {
    const int idx = blockIdx.x * blockDim.x + threadIdx.x;   // N_*K_/8 threads
    const f32x4 a = ((const f32x4*)W)[idx * 2];
    const f32x4 c = ((const f32x4*)W)[idx * 2 + 1];
    union { bf16x8 v; unsigned short u[8]; } pk;
    pk.u[0] = f2bf(a[0]); pk.u[1] = f2bf(a[1]); pk.u[2] = f2bf(a[2]); pk.u[3] = f2bf(a[3]);
    pk.u[4] = f2bf(c[0]); pk.u[5] = f2bf(c[1]); pk.u[6] = f2bf(c[2]); pk.u[7] = f2bf(c[3]);
    *(bf16x8*)(Wbf + (size_t)idx * 8) = pk.v;
}

// ---------------------------------------------------------------------------
// Kernel 3: build A = [gathered context | output] in bf16, row-major [M_,K_]
// ---------------------------------------------------------------------------
__global__ void pack_a(const float* __restrict__ ctx, const float* __restrict__ outp,
                       const int* __restrict__ jbuf, unsigned short* __restrict__ Abf) {
    const int idx = blockIdx.x * blockDim.x + threadIdx.x;   // M_*K_/8 threads
    const int m  = idx >> 7;           // K_/8 = 128 chunks per row
    const int k0 = (idx & 127) * 8;
    const float* src;
    if (k0 < D_) {
        const int b = m >> 10;
        src = ctx + ((size_t)(b * S_ + jbuf[m])) * D_ + k0;   // mix = gather(context)
    } else {
        src = outp + (size_t)m * D_ + (k0 - D_);
    }
    const f32x4 a = ((const f32x4*)src)[0];
    const f32x4 c = ((const f32x4*)src)[1];
    union { bf16x8 v; unsigned short u[8]; } pk;
    pk.u[0] = f2bf(a[0]); pk.u[1] = f2bf(a[1]); pk.u[2] = f2bf(a[2]); pk.u[3] = f2bf(a[3]);
    pk.u[4] = f2bf(c[0]); pk.u[5] = f2bf(c[1]); pk.u[6] = f2bf(c[2]); pk.u[7] = f2bf(c[3]);
    *(bf16x8*)(Abf + (size_t)m * K_ + k0) = pk.v;
}

// ---------------------------------------------------------------------------
// Kernel 4: GEMM (A[M,K] bf16) x (W[N,K] bf16)^T + bias, tanh epilogue.
// m97 structure: 128x128 tile, BK=64, 4 waves, 4x4 of 16x16x32 MFMA per wave,
// global_load_lds width-16 staging (PACKED=true). PACKED=false converts
// fp32 sources inline during staging (ws-lean fallback).
// ---------------------------------------------------------------------------
#define BM 128
#define BN 128
#define BK 64

template <bool PACKED>
__global__ __launch_bounds__(256)
void gemm_bt_tanh(const unsigned short* __restrict__ Abf,
                  const unsigned short* __restrict__ Wbf,
                  const float* __restrict__ bias,
                  float* __restrict__ out,
                  const float* __restrict__ ctx,
                  const float* __restrict__ outp,
                  const int* __restrict__ jbuf) {
    __shared__ unsigned short As[BM * BK];   // 16 KB, row-major [row][k]
    __shared__ unsigned short Bs[BN * BK];   // 16 KB, row-major [n][k]

    const int tid  = threadIdx.x;
    const int lane = tid & 63;
    const int wave = tid >> 6;
    const int wm = wave >> 1, wn = wave & 1;     // 2x2 waves -> 64x64 each
    const int l16 = lane & 15, quad = lane >> 4;

    const int bm = blockIdx.x >> 2;              // 256 m-tiles
    const int bn = blockIdx.x & 3;               // 4 n-tiles
    const int mBase = bm * BM;
    const int nBase = bn * BN;

    f32x4 acc[4][4] = {};

    for (int ko = 0; ko < K_; ko += BK) {
        // ---- stage A (128x64) and B (128x64), 1024 16B-chunks each /256 thr
        #pragma unroll
        for (int it = 0; it < 4; ++it) {
            const int chunk = it * 256 + tid;        // lane-consecutive
            const int row = chunk >> 3;              // 0..127
            const int k8  = (chunk & 7) * 8;
            if (PACKED) {
                const unsigned short* gA = Abf + (size_t)(mBase + row) * K_ + ko + k8;
                __builtin_amdgcn_global_load_lds(
                    (const __attribute__((address_space(1))) void*)gA,
                    (__attribute__((address_space(3))) void*)(As + chunk * 8), 16, 0, 0);
            } else {
                const int kg = ko + k8;
                const int m = mBase + row;
                const float* src;
                if (kg < D_) {
                    const int b = m >> 10;
                    src = ctx + ((size_t)(b * S_ + jbuf[m])) * D_ + kg;
                } else {
                    src = outp + (size_t)m * D_ + (kg - D_);
                }
                const f32x4 a = ((const f32x4*)src)[0];
                const f32x4 c = ((const f32x4*)src)[1];
                union { bf16x8 v; unsigned short u[8]; } pk;
                pk.u[0]=f2bf(a[0]); pk.u[1]=f2bf(a[1]); pk.u[2]=f2bf(a[2]); pk.u[3]=f2bf(a[3]);
                pk.u[4]=f2bf(c[0]); pk.u[5]=f2bf(c[1]); pk.u[6]=f2bf(c[2]); pk.u[7]=f2bf(c[3]);
                *(bf16x8*)(As + chunk * 8) = pk.v;
            }
        }
        #pragma unroll
        for (int it = 0; it < 4; ++it) {
            const int chunk = it * 256 + tid;
            const int row = chunk >> 3;
            const int k8  = (chunk & 7) * 8;
            const unsigned short* gB = Wbf + (size_t)(nBase + row) * K_ + ko + k8;
            __builtin_amdgcn_global_load_lds(
                (const __attribute__((address_space(1))) void*)gB,
                (__attribute__((address_space(3))) void*)(Bs + chunk * 8), 16, 0, 0);
        }
        __syncthreads();

        // ---- 2 K-steps of 32; 16 MFMA each
        #pragma unroll
        for (int ks = 0; ks < 2; ++ks) {
            bf16x8 af[4], bfr[4];
            #pragma unroll
            for (int mt = 0; mt < 4; ++mt)
                af[mt] = *(const bf16x8*)&As[(wm * 64 + mt * 16 + l16) * BK + ks * 32 + quad * 8];
            #pragma unroll
            for (int nt = 0; nt < 4; ++nt)
                bfr[nt] = *(const bf16x8*)&Bs[(wn * 64 + nt * 16 + l16) * BK + ks * 32 + quad * 8];
            #pragma unroll
            for (int mt = 0; mt < 4; ++mt)
                #pragma unroll
                for (int nt = 0; nt < 4; ++nt)
                    acc[mt][nt] = __builtin_amdgcn_mfma_f32_16x16x32_bf16(
                        af[mt], bfr[nt], acc[mt][nt], 0, 0, 0);
        }
        __syncthreads();
    }

    // ---- epilogue: tanh(acc + bias), fp32 store
    #pragma unroll
    for (int nt = 0; nt < 4; ++nt) {
        const int n = nBase + wn * 64 + nt * 16 + l16;
        const float bv = bias[n];
        #pragma unroll
        for (int mt = 0; mt < 4; ++mt) {
            #pragma unroll
            for (int r = 0; r < 4; ++r) {
                const int m = mBase + wm * 64 + mt * 16 + quad * 4 + r;
                out[(size_t)m * N_ + n] = tanhf(acc[mt][nt][r] + bv);
            }
        }
    }
}

// ---------------------------------------------------------------------------
extern "C" void kernel_launch(void* const* d_in, const int* in_sizes, int n_in,
                              void* d_out, int out_size, void* d_ws, size_t ws_size,
                              hipStream_t stream) {
    const int*   iv   = (const int*)d_in[0];    // input_var [B,T] (int)
    const float* outp = (const float*)d_in[1];  // output   [B,T,D]
    const float* ctx  = (const float*)d_in[2];  // context  [B,S,D]
    // d_in[3] = di (unused by reference body)
    const float* W    = (const float*)d_in[4];  // [D, 2D]
    const float* bias = (const float*)d_in[5];  // [D]

    float* out  = (float*)d_out;                       // [B,T,D]
    float* attn = out + (size_t)M_ * N_;               // [B,T,S]

    // workspace layout: j[M_] int32 | Wbf[N_*K_] bf16 | Abf[M_*K_] bf16
    int* jbuf = (int*)d_ws;
    unsigned short* Wbf = (unsigned short*)((char*)d_ws + (size_t)M_ * 4);
    unsigned short* Abf = (unsigned short*)((char*)d_ws + (size_t)M_ * 4 + (size_t)N_ * K_ * 2);
    const size_t need_full = (size_t)M_ * 4 + (size_t)N_ * K_ * 2 + (size_t)M_ * K_ * 2;

    hipMemsetAsync(attn, 0, (size_t)M_ * S_ * sizeof(float), stream);
    align_kernel<<<B_, 64, 0, stream>>>(iv, jbuf, attn);
    pack_w<<<(N_ * K_ / 8) / 256, 256, 0, stream>>>(W, Wbf);

    if (ws_size >= need_full) {
        pack_a<<<(M_ * K_ / 8) / 256, 256, 0, stream>>>(ctx, outp, jbuf, Abf);
        gemm_bt_tanh<true><<<(M_ / BM) * (N_ / BN), 256, 0, stream>>>(
            Abf, Wbf, bias, out, ctx, outp, jbuf);
    } else {
        gemm_bt_tanh<false><<<(M_ / BM) * (N_ / BN), 256, 0, stream>>>(
            Abf, Wbf, bias, out, ctx, outp, jbuf);
    }
}